// Round 4
// baseline (401.861 us; speedup 1.0000x reference)
//
#include <hip/hip_runtime.h>

// ---------------------------------------------------------------------------
// AttentionTemporalEncoder on MI355X (gfx950)
// B=32, T=512, HIDDEN=1024, NH=16, HD=64
//
// R4 change: gemm1 split into 3 kernels (Q, K, V) with identical structure
// and total work — a measurement refactor so the rocprof top-5 stops being
// monopolized by one 139-us dispatch and reveals attn/gemm2/xpose durations.
// attn/gemm2 unchanged from R3.
// ---------------------------------------------------------------------------

typedef _Float16 half8 __attribute__((ext_vector_type(8)));
typedef _Float16 half4 __attribute__((ext_vector_type(4)));
typedef float floatx4 __attribute__((ext_vector_type(4)));

#define HID 1024
#define TT 512
#define NB 32

__device__ __forceinline__ void gload16(const void* g, void* l) {
    __builtin_amdgcn_global_load_lds(
        (const __attribute__((address_space(1))) unsigned int*)g,
        (__attribute__((address_space(3))) unsigned int*)l, 16, 0, 0);
}

// monotone float->uint key: preserves order for atomicMax; 0 is below all keys
__device__ __forceinline__ unsigned fkey(float f) {
    unsigned u = __float_as_uint(f);
    return (u & 0x80000000u) ? ~u : (u | 0x80000000u);
}
__device__ __forceinline__ float funkey(unsigned k) {
    unsigned u = (k & 0x80000000u) ? (k ^ 0x80000000u) : ~k;
    return __uint_as_float(u);
}

// ---------------------------------------------------------------------------
__global__ __launch_bounds__(256) void convw_kernel(
    const float* __restrict__ Wq, const float* __restrict__ Wk,
    const float* __restrict__ Wv, const float* __restrict__ Wo,
    _Float16* __restrict__ Wcat)
{
    int i = blockIdx.x * 256 + threadIdx.x;        // 0 .. 4M
    int sec = i >> 20;
    int off = i & ((1 << 20) - 1);
    const float* src = (sec == 0) ? Wq : (sec == 1) ? Wk : (sec == 2) ? Wv : Wo;
    Wcat[i] = (_Float16)src[off];
}

__global__ __launch_bounds__(256) void xpose_kernel(
    const float* __restrict__ x, _Float16* __restrict__ xT)
{
    __shared__ float tile[32][33];
    int b = blockIdx.z, h0 = blockIdx.y * 32, t0 = blockIdx.x * 32;
    int tx = threadIdx.x & 31, ty = threadIdx.x >> 5;   // ty 0..7
    const float* xb = x + ((size_t)b * HID + h0) * TT + t0;
    for (int p = 0; p < 4; p++)
        tile[ty + 8 * p][tx] = xb[(ty + 8 * p) * TT + tx];
    __syncthreads();
    _Float16* xTb = xT + ((size_t)b * TT + t0) * HID + h0;
    for (int p = 0; p < 4; p++)
        xTb[(ty + 8 * p) * HID + tx] = (_Float16)tile[tx][ty + 8 * p];
}

__global__ __launch_bounds__(256) void initmax_kernel(unsigned* __restrict__ omax)
{
    omax[blockIdx.x * 256 + threadIdx.x] = 0u;
}

// ---------------------------------------------------------------------------
// GEMM mainloop: C(128x128) += A(128xK) * B^T, both row-major with K
// contiguous, lda = ldb = 1024. LDS tiles 128x64 halves, unpadded, granule
// swizzle p = g ^ (row & 7). Staging via global_load_lds width=16.
__device__ __forceinline__ void gemm_mainloop(
    const _Float16* __restrict__ Arows,   // W   + m0*1024
    const _Float16* __restrict__ Brows,   // act + n0*1024  (rows = n, cols = k)
    _Float16* aT, _Float16* bT, floatx4 acc[4][4], int tid)
{
    const int lane = tid & 63, wid = tid >> 6;
    const int l15 = lane & 15, quad = lane >> 4;
    const int wm = (wid >> 1) * 64, wn = (wid & 1) * 64;

    const int srow = lane >> 3;
    const int sg = (lane & 7) ^ srow;
    const _Float16* ga = Arows + (size_t)(wid * 32 + srow) * 1024 + sg * 8;
    const _Float16* gb = Brows + (size_t)(wid * 32 + srow) * 1024 + sg * 8;
    _Float16* la = aT + wid * 32 * 64;
    _Float16* lb = bT + wid * 32 * 64;

    const int pa = quad ^ (l15 & 7);

    for (int k0 = 0; k0 < 1024; k0 += 64) {
        for (int p = 0; p < 4; p++) {
            gload16(ga + k0 + p * 8 * 1024, la + p * 8 * 64);
            gload16(gb + k0 + p * 8 * 1024, lb + p * 8 * 64);
        }
        __syncthreads();
        for (int kk = 0; kk < 2; kk++) {
            const int pg = kk ? (pa ^ 4) : pa;
            half8 af[4], bf[4];
            for (int mi = 0; mi < 4; mi++)
                af[mi] = *(half8*)(aT + (wm + mi * 16 + l15) * 64 + pg * 8);
            for (int ni = 0; ni < 4; ni++)
                bf[ni] = *(half8*)(bT + (wn + ni * 16 + l15) * 64 + pg * 8);
            for (int mi = 0; mi < 4; mi++)
                for (int ni = 0; ni < 4; ni++)
                    acc[mi][ni] = __builtin_amdgcn_mfma_f32_16x16x32_f16(
                        af[mi], bf[ni], acc[mi][ni], 0, 0, 0);
        }
        __syncthreads();
    }
}

// Q/K-style kernel: C -> [t][c] layout via LDS-transposed epilogue.
// grid (4, 8, 32): m0 = blockIdx.y*128 within this weight section.
__global__ __launch_bounds__(256) void gemm1qk_kernel(
    const _Float16* __restrict__ Wsec,    // Wcat section (q or k)
    const float* __restrict__ bias,
    const _Float16* __restrict__ xT,
    _Float16* __restrict__ dst)           // QT or KT
{
    __shared__ __align__(16) char smem[34816];   // 2x16 KB tiles | 128x136 tr
    _Float16* aT = (_Float16*)smem;
    _Float16* bTl = aT + 128 * 64;

    const int tid = threadIdx.x;
    const int m0 = blockIdx.y * 128, n0 = blockIdx.x * 128, b = blockIdx.z;
    const int lane = tid & 63, wid = tid >> 6;
    const int l15 = lane & 15, quad = lane >> 4;
    const int wm = (wid >> 1) * 64, wn = (wid & 1) * 64;

    floatx4 acc[4][4] = {};
    gemm_mainloop(Wsec + (size_t)m0 * 1024,
                  xT + ((size_t)b * TT + n0) * HID,
                  aT, bTl, acc, tid);

    _Float16* tr = (_Float16*)smem;     // 128 x 136 halves = 34816 B
    for (int mi = 0; mi < 4; mi++) {
        float bs[4];
        for (int r = 0; r < 4; r++)
            bs[r] = bias[m0 + wm + mi * 16 + quad * 4 + r];
        for (int ni = 0; ni < 4; ni++) {
            half4 pk;
            for (int r = 0; r < 4; r++)
                pk[r] = (_Float16)(acc[mi][ni][r] + bs[r]);
            int tl = wn + ni * 16 + l15;
            int ol = wm + mi * 16 + quad * 4;
            *(half4*)(tr + tl * 136 + ol) = pk;
        }
    }
    __syncthreads();
    int tl = tid >> 1, cb = (tid & 1) * 64;
    for (int ch = 0; ch < 8; ch++) {
        uint4 v = *(uint4*)(tr + tl * 136 + cb + ch * 8);
        *(uint4*)(dst + ((size_t)b * TT + n0 + tl) * HID + m0 + cb + ch * 8) = v;
    }
}

// V kernel: direct [c][t] stores. grid (4, 8, 32)
__global__ __launch_bounds__(256) void gemm1v_kernel(
    const _Float16* __restrict__ Wsec,    // Wcat + 2M
    const float* __restrict__ bv,
    const _Float16* __restrict__ xT,
    _Float16* __restrict__ Vb)
{
    __shared__ __align__(16) char smem[2 * 128 * 64 * 2];
    _Float16* aT = (_Float16*)smem;
    _Float16* bTl = aT + 128 * 64;

    const int tid = threadIdx.x;
    const int m0 = blockIdx.y * 128, n0 = blockIdx.x * 128, b = blockIdx.z;
    const int lane = tid & 63, wid = tid >> 6;
    const int l15 = lane & 15, quad = lane >> 4;
    const int wm = (wid >> 1) * 64, wn = (wid & 1) * 64;

    floatx4 acc[4][4] = {};
    gemm_mainloop(Wsec + (size_t)m0 * 1024,
                  xT + ((size_t)b * TT + n0) * HID,
                  aT, bTl, acc, tid);

    for (int mi = 0; mi < 4; mi++) {
        float bs[4];
        for (int r = 0; r < 4; r++)
            bs[r] = bv[m0 + wm + mi * 16 + quad * 4 + r];
        for (int ni = 0; ni < 4; ni++) {
            int t = n0 + wn + ni * 16 + l15;
            for (int r = 0; r < 4; r++) {
                int o = m0 + wm + mi * 16 + quad * 4 + r;
                Vb[((size_t)b * HID + o) * TT + t] =
                    (_Float16)(acc[mi][ni][r] + bs[r]);
            }
        }
    }
}

// ---------------------------------------------------------------------------
// attention: grid (8 q-tiles, 16 heads, 32 batch); block = 256 (4 waves)
__global__ __launch_bounds__(256) void attn_kernel(
    const _Float16* __restrict__ QT, const _Float16* __restrict__ KT,
    const _Float16* __restrict__ Vb, const int* __restrict__ mask,
    _Float16* __restrict__ OcT)
{
    __shared__ __align__(16) _Float16 qs[64 * 64];   // [q][d]  swizzled
    __shared__ __align__(16) _Float16 ks[64 * 64];   // [t][d]  swizzled
    __shared__ __align__(16) _Float16 vs[64 * 64];   // [d][t]  swizzled
    __shared__ __align__(16) _Float16 ps[64 * 64];   // [q][t]  swizzled
    __shared__ int ms[64];

    const int b = blockIdx.z, hd = blockIdx.y, i0 = blockIdx.x * 64;
    const int tid = threadIdx.x;
    const int lane = tid & 63, wid = tid >> 6;
    const int l15 = lane & 15, quad = lane >> 4;

    const _Float16* QTb = QT + ((size_t)b * TT + i0) * HID + hd * 64;
    const _Float16* KTb = KT + (size_t)b * TT * HID + hd * 64;
    const _Float16* Vbb = Vb + ((size_t)b * HID + hd * 64) * TT;
    const int* mb = mask + b * TT;

    const int srow = lane >> 3;                 // 0..7 == row&7
    const int sg = (lane & 7) ^ srow;

    for (int p = 0; p < 2; p++) {
        int r = p * 32 + wid * 8 + srow;
        gload16(QTb + (size_t)r * HID + sg * 8, qs + (p * 32 + wid * 8) * 64);
    }
    __syncthreads();

    const int pa = quad ^ (l15 & 7);
    half8 bq0 = *(half8*)(qs + (wid * 16 + l15) * 64 + pa * 8);
    half8 bq1 = *(half8*)(qs + (wid * 16 + l15) * 64 + (pa ^ 4) * 8);

    floatx4 oacc[4] = {};
    float rs = 0.f;

    for (int jc = 0; jc < 8; jc++) {
        const int t0 = jc * 64;
        __syncthreads();    // protect ks/vs from previous iteration's readers
        for (int p = 0; p < 2; p++) {
            int r = p * 32 + wid * 8 + srow;
            gload16(KTb + (size_t)(t0 + r) * HID + sg * 8,
                    ks + (p * 32 + wid * 8) * 64);
            gload16(Vbb + (size_t)r * TT + t0 + sg * 8,
                    vs + (p * 32 + wid * 8) * 64);
        }
        if (tid < 64) ms[tid] = mb[t0 + tid];
        __syncthreads();

        // S^T = K Q^T / 8 -> mask/clip/exp -> packed b64 into ps[q][t]
        for (int jt = 0; jt < 4; jt++) {
            half8 ka0 = *(half8*)(ks + (jt * 16 + l15) * 64 + pa * 8);
            half8 ka1 = *(half8*)(ks + (jt * 16 + l15) * 64 + (pa ^ 4) * 8);
            floatx4 sc = {0.f, 0.f, 0.f, 0.f};
            sc = __builtin_amdgcn_mfma_f32_16x16x32_f16(ka0, bq0, sc, 0, 0, 0);
            sc = __builtin_amdgcn_mfma_f32_16x16x32_f16(ka1, bq1, sc, 0, 0, 0);
            int4 m4 = *(const int4*)(ms + jt * 16 + quad * 4);
            half4 pk;
            for (int r = 0; r < 4; r++) {
                float s = sc[r] * 0.125f;
                s = fminf(fmaxf(s, -50.f), 50.f);
                s = (&m4.x)[r] ? s : -50.f;
                float e = __expf(s);
                rs += e;
                pk[r] = (_Float16)e;
            }
            int col = jt * 16 + quad * 4;
            *(half4*)(ps + (wid * 16 + l15) * 64 +
                      ((col >> 3) ^ (l15 & 7)) * 8 + (col & 7)) = pk;
        }
        __syncthreads();

        // O += P V^T
        for (int kc = 0; kc < 2; kc++) {
            int g = kc * 4 + quad;
            half8 ap = *(half8*)(ps + (wid * 16 + l15) * 64 + (g ^ (l15 & 7)) * 8);
            for (int d4 = 0; d4 < 4; d4++) {
                half8 bv8 = *(half8*)(vs + (d4 * 16 + l15) * 64 + (g ^ (l15 & 7)) * 8);
                oacc[d4] = __builtin_amdgcn_mfma_f32_16x16x32_f16(ap, bv8, oacc[d4], 0, 0, 0);
            }
        }
    }

    rs += __shfl_xor(rs, 16, 64);
    rs += __shfl_xor(rs, 32, 64);
    float inv[4];
    for (int r = 0; r < 4; r++)
        inv[r] = 1.0f / __shfl(rs, quad * 4 + r, 64);

    for (int d4 = 0; d4 < 4; d4++)
        for (int r = 0; r < 4; r++) {
            int t = i0 + wid * 16 + quad * 4 + r;
            int c = hd * 64 + d4 * 16 + l15;
            OcT[((size_t)b * TT + t) * HID + c] = (_Float16)(oacc[d4][r] * inv[r]);
        }
}

// ---------------------------------------------------------------------------
// gemm2: out2 = Wo @ Oc ; epilogue: rowwise max over this block's 128 t-cols,
// atomicMax into omax (monotone key). grid (4, 8, 32)
__global__ __launch_bounds__(256) void gemm2_kernel(
    const _Float16* __restrict__ Wo16, const _Float16* __restrict__ OcT,
    unsigned* __restrict__ omax)
{
    __shared__ __align__(16) char smem[2 * 128 * 64 * 2];
    _Float16* aT = (_Float16*)smem;
    _Float16* bTl = aT + 128 * 64;

    const int tid = threadIdx.x;
    const int m0 = blockIdx.y * 128, n0 = blockIdx.x * 128, b = blockIdx.z;
    const int lane = tid & 63, wid = tid >> 6;
    const int l15 = lane & 15, quad = lane >> 4;
    const int wm = (wid >> 1) * 64;

    floatx4 acc[4][4] = {};
    gemm_mainloop(Wo16 + (size_t)m0 * 1024,
                  OcT + ((size_t)b * TT + n0) * HID,
                  aT, bTl, acc, tid);

    for (int mi = 0; mi < 4; mi++)
        for (int r = 0; r < 4; r++) {
            float v = acc[mi][0][r];
            for (int ni = 1; ni < 4; ni++) v = fmaxf(v, acc[mi][ni][r]);
            for (int d = 1; d < 16; d <<= 1) v = fmaxf(v, __shfl_xor(v, d, 64));
            if (l15 == 0) {
                int o = m0 + wm + mi * 16 + quad * 4 + r;
                atomicMax(&omax[b * HID + o], fkey(v));
            }
        }
}

__global__ __launch_bounds__(256) void final_kernel(
    const unsigned* __restrict__ omax, const float* __restrict__ bo,
    float* __restrict__ out)
{
    int i = blockIdx.x * 256 + threadIdx.x;   // 0 .. 32767
    out[i] = funkey(omax[i]) + bo[i & 1023];
}

// ---------------------------------------------------------------------------
extern "C" void kernel_launch(void* const* d_in, const int* in_sizes, int n_in,
                              void* d_out, int out_size, void* d_ws, size_t ws_size,
                              hipStream_t stream)
{
    const float* x  = (const float*)d_in[0];
    const int* mask = (const int*)d_in[1];
    const float* Wq = (const float*)d_in[2];
    const float* bq = (const float*)d_in[3];
    const float* Wk = (const float*)d_in[4];
    const float* bk = (const float*)d_in[5];
    const float* Wv = (const float*)d_in[6];
    const float* bv = (const float*)d_in[7];
    const float* Wo = (const float*)d_in[8];
    const float* bo = (const float*)d_in[9];
    float* out = (float*)d_out;

    char* ws = (char*)d_ws;
    _Float16* Wcat = (_Float16*)(ws);                      //   8 MiB (q,k,v,o)
    _Float16* xT   = (_Float16*)(ws + (8ull  << 20));      //  32 MiB
    _Float16* QT   = (_Float16*)(ws + (40ull << 20));      //  32 MiB
    _Float16* KT   = (_Float16*)(ws + (72ull << 20));      //  32 MiB
    _Float16* Vb   = (_Float16*)(ws + (104ull << 20));     //  32 MiB
    _Float16* OcT  = (_Float16*)(ws + (136ull << 20));     //  32 MiB
    unsigned* omax = (unsigned*)(ws + (168ull << 20));     // 128 KiB

    convw_kernel<<<16384, 256, 0, stream>>>(Wq, Wk, Wv, Wo, Wcat);
    xpose_kernel<<<dim3(16, 32, 32), 256, 0, stream>>>(x, xT);
    initmax_kernel<<<128, 256, 0, stream>>>(omax);
    gemm1qk_kernel<<<dim3(4, 8, 32), 256, 0, stream>>>(Wcat, bq, xT, QT);
    gemm1qk_kernel<<<dim3(4, 8, 32), 256, 0, stream>>>(Wcat + (1ull << 20), bk, xT, KT);
    gemm1v_kernel<<<dim3(4, 8, 32), 256, 0, stream>>>(Wcat + (2ull << 20), bv, xT, Vb);
    attn_kernel<<<dim3(8, 16, 32), 256, 0, stream>>>(QT, KT, Vb, mask, OcT);
    gemm2_kernel<<<dim3(4, 8, 32), 256, 0, stream>>>(Wcat + (3ull << 20), OcT, omax);
    final_kernel<<<128, 256, 0, stream>>>(omax, bo, out);
}

// Round 6
// 388.960 us; speedup vs baseline: 1.0332x; 1.0332x over previous
//
#include <hip/hip_runtime.h>

// ---------------------------------------------------------------------------
// AttentionTemporalEncoder on MI355X (gfx950)
// B=32, T=512, HIDDEN=1024, NH=16, HD=64
//
// R6 = R5 with the cvt_pkrtz type mismatch fixed (bit_cast through unsigned).
//  - attn block owns 4 q-tiles (grid 2,16,32): K/V staged once per 64-t
//    chunk, reused across tiles -> K/V HBM duplication 8x -> <=2x.
//  - Q pre-scaled by 0.125 in gemm1; softmax inner loop = clamp+exp+add+pack.
//  - mask folded into per-t upper bound: clamp(s, -50, mask?50:-50).
// gemm1(q/k/v split), gemm2, xpose, convw unchanged from R4.
// ---------------------------------------------------------------------------

typedef _Float16 half8 __attribute__((ext_vector_type(8)));
typedef _Float16 half4 __attribute__((ext_vector_type(4)));
typedef __fp16 fp16x2 __attribute__((ext_vector_type(2)));
typedef float floatx4 __attribute__((ext_vector_type(4)));
typedef unsigned uintx2 __attribute__((ext_vector_type(2)));

#define HID 1024
#define TT 512
#define NB 32
#define QSCALE 0.125f
#define SBOUND 50.0f

__device__ __forceinline__ void gload16(const void* g, void* l) {
    __builtin_amdgcn_global_load_lds(
        (const __attribute__((address_space(1))) unsigned int*)g,
        (__attribute__((address_space(3))) unsigned int*)l, 16, 0, 0);
}

// monotone float->uint key: preserves order for atomicMax; 0 is below all keys
__device__ __forceinline__ unsigned fkey(float f) {
    unsigned u = __float_as_uint(f);
    return (u & 0x80000000u) ? ~u : (u | 0x80000000u);
}
__device__ __forceinline__ float funkey(unsigned k) {
    unsigned u = (k & 0x80000000u) ? (k ^ 0x80000000u) : ~k;
    return __uint_as_float(u);
}

// ---------------------------------------------------------------------------
__global__ __launch_bounds__(256) void convw_kernel(
    const float* __restrict__ Wq, const float* __restrict__ Wk,
    const float* __restrict__ Wv, const float* __restrict__ Wo,
    _Float16* __restrict__ Wcat)
{
    int i = blockIdx.x * 256 + threadIdx.x;        // 0 .. 4M
    int sec = i >> 20;
    int off = i & ((1 << 20) - 1);
    const float* src = (sec == 0) ? Wq : (sec == 1) ? Wk : (sec == 2) ? Wv : Wo;
    Wcat[i] = (_Float16)src[off];
}

__global__ __launch_bounds__(256) void xpose_kernel(
    const float* __restrict__ x, _Float16* __restrict__ xT)
{
    __shared__ float tile[32][33];
    int b = blockIdx.z, h0 = blockIdx.y * 32, t0 = blockIdx.x * 32;
    int tx = threadIdx.x & 31, ty = threadIdx.x >> 5;   // ty 0..7
    const float* xb = x + ((size_t)b * HID + h0) * TT + t0;
    for (int p = 0; p < 4; p++)
        tile[ty + 8 * p][tx] = xb[(ty + 8 * p) * TT + tx];
    __syncthreads();
    _Float16* xTb = xT + ((size_t)b * TT + t0) * HID + h0;
    for (int p = 0; p < 4; p++)
        xTb[(ty + 8 * p) * HID + tx] = (_Float16)tile[tx][ty + 8 * p];
}

__global__ __launch_bounds__(256) void initmax_kernel(unsigned* __restrict__ omax)
{
    omax[blockIdx.x * 256 + threadIdx.x] = 0u;
}

// ---------------------------------------------------------------------------
// GEMM mainloop: C(128x128) += A(128xK) * B^T, both row-major with K
// contiguous, lda = ldb = 1024. LDS tiles 128x64 halves, unpadded, granule
// swizzle p = g ^ (row & 7). Staging via global_load_lds width=16.
__device__ __forceinline__ void gemm_mainloop(
    const _Float16* __restrict__ Arows,   // W   + m0*1024
    const _Float16* __restrict__ Brows,   // act + n0*1024  (rows = n, cols = k)
    _Float16* aT, _Float16* bT, floatx4 acc[4][4], int tid)
{
    const int lane = tid & 63, wid = tid >> 6;
    const int l15 = lane & 15, quad = lane >> 4;
    const int wm = (wid >> 1) * 64, wn = (wid & 1) * 64;

    const int srow = lane >> 3;
    const int sg = (lane & 7) ^ srow;
    const _Float16* ga = Arows + (size_t)(wid * 32 + srow) * 1024 + sg * 8;
    const _Float16* gb = Brows + (size_t)(wid * 32 + srow) * 1024 + sg * 8;
    _Float16* la = aT + wid * 32 * 64;
    _Float16* lb = bT + wid * 32 * 64;

    const int pa = quad ^ (l15 & 7);

    for (int k0 = 0; k0 < 1024; k0 += 64) {
        for (int p = 0; p < 4; p++) {
            gload16(ga + k0 + p * 8 * 1024, la + p * 8 * 64);
            gload16(gb + k0 + p * 8 * 1024, lb + p * 8 * 64);
        }
        __syncthreads();
        for (int kk = 0; kk < 2; kk++) {
            const int pg = kk ? (pa ^ 4) : pa;
            half8 af[4], bf[4];
            for (int mi = 0; mi < 4; mi++)
                af[mi] = *(half8*)(aT + (wm + mi * 16 + l15) * 64 + pg * 8);
            for (int ni = 0; ni < 4; ni++)
                bf[ni] = *(half8*)(bT + (wn + ni * 16 + l15) * 64 + pg * 8);
            for (int mi = 0; mi < 4; mi++)
                for (int ni = 0; ni < 4; ni++)
                    acc[mi][ni] = __builtin_amdgcn_mfma_f32_16x16x32_f16(
                        af[mi], bf[ni], acc[mi][ni], 0, 0, 0);
        }
        __syncthreads();
    }
}

// Q/K-style kernel: C -> [t][c] layout via LDS-transposed epilogue.
// grid (4, 8, 32). `scale` folds the attention 1/sqrt(d) into Q.
__global__ __launch_bounds__(256) void gemm1qk_kernel(
    const _Float16* __restrict__ Wsec,    // Wcat section (q or k)
    const float* __restrict__ bias,
    const _Float16* __restrict__ xT,
    _Float16* __restrict__ dst,           // QT or KT
    float scale)
{
    __shared__ __align__(16) char smem[34816];   // 2x16 KB tiles | 128x136 tr
    _Float16* aT = (_Float16*)smem;
    _Float16* bTl = aT + 128 * 64;

    const int tid = threadIdx.x;
    const int m0 = blockIdx.y * 128, n0 = blockIdx.x * 128, b = blockIdx.z;
    const int lane = tid & 63, wid = tid >> 6;
    const int l15 = lane & 15, quad = lane >> 4;
    const int wm = (wid >> 1) * 64, wn = (wid & 1) * 64;

    floatx4 acc[4][4] = {};
    gemm_mainloop(Wsec + (size_t)m0 * 1024,
                  xT + ((size_t)b * TT + n0) * HID,
                  aT, bTl, acc, tid);

    _Float16* tr = (_Float16*)smem;     // 128 x 136 halves = 34816 B
    for (int mi = 0; mi < 4; mi++) {
        float bs[4];
        for (int r = 0; r < 4; r++)
            bs[r] = bias[m0 + wm + mi * 16 + quad * 4 + r];
        for (int ni = 0; ni < 4; ni++) {
            half4 pk;
            for (int r = 0; r < 4; r++)
                pk[r] = (_Float16)((acc[mi][ni][r] + bs[r]) * scale);
            int tl = wn + ni * 16 + l15;
            int ol = wm + mi * 16 + quad * 4;
            *(half4*)(tr + tl * 136 + ol) = pk;
        }
    }
    __syncthreads();
    int tl = tid >> 1, cb = (tid & 1) * 64;
    for (int ch = 0; ch < 8; ch++) {
        uint4 v = *(uint4*)(tr + tl * 136 + cb + ch * 8);
        *(uint4*)(dst + ((size_t)b * TT + n0 + tl) * HID + m0 + cb + ch * 8) = v;
    }
}

// V kernel: direct [c][t] stores. grid (4, 8, 32)
__global__ __launch_bounds__(256) void gemm1v_kernel(
    const _Float16* __restrict__ Wsec,    // Wcat + 2M
    const float* __restrict__ bv,
    const _Float16* __restrict__ xT,
    _Float16* __restrict__ Vb)
{
    __shared__ __align__(16) char smem[2 * 128 * 64 * 2];
    _Float16* aT = (_Float16*)smem;
    _Float16* bTl = aT + 128 * 64;

    const int tid = threadIdx.x;
    const int m0 = blockIdx.y * 128, n0 = blockIdx.x * 128, b = blockIdx.z;
    const int lane = tid & 63, wid = tid >> 6;
    const int l15 = lane & 15, quad = lane >> 4;
    const int wm = (wid >> 1) * 64, wn = (wid & 1) * 64;

    floatx4 acc[4][4] = {};
    gemm_mainloop(Wsec + (size_t)m0 * 1024,
                  xT + ((size_t)b * TT + n0) * HID,
                  aT, bTl, acc, tid);

    for (int mi = 0; mi < 4; mi++) {
        float bs[4];
        for (int r = 0; r < 4; r++)
            bs[r] = bv[m0 + wm + mi * 16 + quad * 4 + r];
        for (int ni = 0; ni < 4; ni++) {
            int t = n0 + wn + ni * 16 + l15;
            for (int r = 0; r < 4; r++) {
                int o = m0 + wm + mi * 16 + quad * 4 + r;
                Vb[((size_t)b * HID + o) * TT + t] =
                    (_Float16)(acc[mi][ni][r] + bs[r]);
            }
        }
    }
}

// ---------------------------------------------------------------------------
// attention: grid (2 q-groups, 16 heads, 32 batch); block = 256 (4 waves).
// Each block owns 4 q-tiles (256 q rows). K/V staged per 64-t chunk, reused
// across the 4 tiles. Q pre-scaled by 0.125 in gemm1. S computed transposed
// (mfma(k,q)); mask folded into per-t upper bound for the clamp.
__global__ __launch_bounds__(256) void attn_kernel(
    const _Float16* __restrict__ QT, const _Float16* __restrict__ KT,
    const _Float16* __restrict__ Vb, const int* __restrict__ mask,
    _Float16* __restrict__ OcT)
{
    __shared__ __align__(16) _Float16 ks[64 * 64];   // [t][d]  swizzled
    __shared__ __align__(16) _Float16 vs[64 * 64];   // [d][t]  swizzled
    __shared__ __align__(16) _Float16 ps[64 * 64];   // [q][t]  swizzled
    __shared__ __align__(16) float msf[64];          // mask -> hi bound per t

    const int b = blockIdx.z, hd = blockIdx.y, q0 = blockIdx.x * 256;
    const int tid = threadIdx.x;
    const int lane = tid & 63, wid = tid >> 6;
    const int l15 = lane & 15, quad = lane >> 4;

    const _Float16* QTb = QT + ((size_t)b * TT + q0) * HID + hd * 64;
    const _Float16* KTb = KT + (size_t)b * TT * HID + hd * 64;
    const _Float16* Vbb = Vb + ((size_t)b * HID + hd * 64) * TT;
    const int* mb = mask + b * TT;

    const int srow = lane >> 3;                 // 0..7 == row&7
    const int sg = (lane & 7) ^ srow;
    const int pa = quad ^ (l15 & 7);
    const int pz = l15 & 7;

    // preload Q fragments for 4 tiles (ps used as staging scratch)
    half8 bq[4][2];
    for (int qt = 0; qt < 4; qt++) {
        for (int p = 0; p < 2; p++) {
            int r = p * 32 + wid * 8 + srow;
            gload16(QTb + (size_t)(qt * 64 + r) * HID + sg * 8,
                    ps + (p * 32 + wid * 8) * 64);
        }
        __syncthreads();
        bq[qt][0] = *(half8*)(ps + (wid * 16 + l15) * 64 + pa * 8);
        bq[qt][1] = *(half8*)(ps + (wid * 16 + l15) * 64 + (pa ^ 4) * 8);
        __syncthreads();
    }

    floatx4 oacc[4][4] = {};
    float rs[4] = {0.f, 0.f, 0.f, 0.f};
    const float lo = -SBOUND;

    for (int jc = 0; jc < 8; jc++) {
        const int t0 = jc * 64;
        __syncthreads();    // all waves done reading ks/vs/msf of prev chunk
        for (int p = 0; p < 2; p++) {
            int r = p * 32 + wid * 8 + srow;
            gload16(KTb + (size_t)(t0 + r) * HID + sg * 8,
                    ks + (p * 32 + wid * 8) * 64);
            gload16(Vbb + (size_t)r * TT + t0 + sg * 8,
                    vs + (p * 32 + wid * 8) * 64);
        }
        if (tid < 64) msf[tid] = mb[t0 + tid] ? SBOUND : -SBOUND;
        __syncthreads();

        // per-t clamp upper bounds for this lane's 16 t values, in registers
        floatx4 hi[4];
        for (int jt = 0; jt < 4; jt++)
            hi[jt] = *(floatx4*)(msf + jt * 16 + quad * 4);

        for (int qt = 0; qt < 4; qt++) {
            // S^T chunk: rows t, cols q; each wave covers its 16 q cols
            for (int jt = 0; jt < 4; jt++) {
                half8 ka0 = *(half8*)(ks + (jt * 16 + l15) * 64 + pa * 8);
                half8 ka1 = *(half8*)(ks + (jt * 16 + l15) * 64 + (pa ^ 4) * 8);
                floatx4 sc = {0.f, 0.f, 0.f, 0.f};
                sc = __builtin_amdgcn_mfma_f32_16x16x32_f16(ka0, bq[qt][0], sc, 0, 0, 0);
                sc = __builtin_amdgcn_mfma_f32_16x16x32_f16(ka1, bq[qt][1], sc, 0, 0, 0);
                float e0 = __expf(fminf(fmaxf(sc[0], lo), hi[jt][0]));
                float e1 = __expf(fminf(fmaxf(sc[1], lo), hi[jt][1]));
                float e2 = __expf(fminf(fmaxf(sc[2], lo), hi[jt][2]));
                float e3 = __expf(fminf(fmaxf(sc[3], lo), hi[jt][3]));
                rs[qt] += (e0 + e1) + (e2 + e3);
                unsigned uA = __builtin_bit_cast(
                    unsigned, __builtin_amdgcn_cvt_pkrtz(e0, e1));
                unsigned uB = __builtin_bit_cast(
                    unsigned, __builtin_amdgcn_cvt_pkrtz(e2, e3));
                uintx2 uv = {uA, uB};
                half4 pk = __builtin_bit_cast(half4, uv);
                int g = jt * 2 + (quad >> 1);           // logical t-granule
                *(half4*)(ps + (wid * 16 + l15) * 64 + (g ^ pz) * 8 +
                          (quad & 1) * 4) = pk;
            }
            // O[qt] += P V^T   (wave reads only its own ps rows — no barrier)
            for (int kc = 0; kc < 2; kc++) {
                int g = kc * 4 + quad;
                half8 ap = *(half8*)(ps + (wid * 16 + l15) * 64 + (g ^ pz) * 8);
                for (int d4 = 0; d4 < 4; d4++) {
                    half8 bv8 = *(half8*)(vs + (d4 * 16 + l15) * 64 + (g ^ pz) * 8);
                    oacc[qt][d4] = __builtin_amdgcn_mfma_f32_16x16x32_f16(
                        ap, bv8, oacc[qt][d4], 0, 0, 0);
                }
            }
        }
    }

    // normalize and write Oc in [t][c] layout
    for (int qt = 0; qt < 4; qt++) {
        float s = rs[qt];
        s += __shfl_xor(s, 16, 64);
        s += __shfl_xor(s, 32, 64);
        s = 1.0f / s;
        float inv[4];
        for (int r = 0; r < 4; r++) inv[r] = __shfl(s, quad * 4 + r, 64);
        for (int d4 = 0; d4 < 4; d4++)
            for (int r = 0; r < 4; r++) {
                int t = q0 + qt * 64 + wid * 16 + quad * 4 + r;
                int c = hd * 64 + d4 * 16 + l15;
                OcT[((size_t)b * TT + t) * HID + c] =
                    (_Float16)(oacc[qt][d4][r] * inv[r]);
            }
    }
}

// ---------------------------------------------------------------------------
// gemm2: out2 = Wo @ Oc ; epilogue: rowwise max over this block's 128 t-cols,
// atomicMax into omax (monotone key). grid (4, 8, 32)
__global__ __launch_bounds__(256) void gemm2_kernel(
    const _Float16* __restrict__ Wo16, const _Float16* __restrict__ OcT,
    unsigned* __restrict__ omax)
{
    __shared__ __align__(16) char smem[2 * 128 * 64 * 2];
    _Float16* aT = (_Float16*)smem;
    _Float16* bTl = aT + 128 * 64;

    const int tid = threadIdx.x;
    const int m0 = blockIdx.y * 128, n0 = blockIdx.x * 128, b = blockIdx.z;
    const int lane = tid & 63, wid = tid >> 6;
    const int l15 = lane & 15, quad = lane >> 4;
    const int wm = (wid >> 1) * 64;

    floatx4 acc[4][4] = {};
    gemm_mainloop(Wo16 + (size_t)m0 * 1024,
                  OcT + ((size_t)b * TT + n0) * HID,
                  aT, bTl, acc, tid);

    for (int mi = 0; mi < 4; mi++)
        for (int r = 0; r < 4; r++) {
            float v = acc[mi][0][r];
            for (int ni = 1; ni < 4; ni++) v = fmaxf(v, acc[mi][ni][r]);
            for (int d = 1; d < 16; d <<= 1) v = fmaxf(v, __shfl_xor(v, d, 64));
            if (l15 == 0) {
                int o = m0 + wm + mi * 16 + quad * 4 + r;
                atomicMax(&omax[b * HID + o], fkey(v));
            }
        }
}

__global__ __launch_bounds__(256) void final_kernel(
    const unsigned* __restrict__ omax, const float* __restrict__ bo,
    float* __restrict__ out)
{
    int i = blockIdx.x * 256 + threadIdx.x;   // 0 .. 32767
    out[i] = funkey(omax[i]) + bo[i & 1023];
}

// ---------------------------------------------------------------------------
extern "C" void kernel_launch(void* const* d_in, const int* in_sizes, int n_in,
                              void* d_out, int out_size, void* d_ws, size_t ws_size,
                              hipStream_t stream)
{
    const float* x  = (const float*)d_in[0];
    const int* mask = (const int*)d_in[1];
    const float* Wq = (const float*)d_in[2];
    const float* bq = (const float*)d_in[3];
    const float* Wk = (const float*)d_in[4];
    const float* bk = (const float*)d_in[5];
    const float* Wv = (const float*)d_in[6];
    const float* bv = (const float*)d_in[7];
    const float* Wo = (const float*)d_in[8];
    const float* bo = (const float*)d_in[9];
    float* out = (float*)d_out;

    char* ws = (char*)d_ws;
    _Float16* Wcat = (_Float16*)(ws);                      //   8 MiB (q,k,v,o)
    _Float16* xT   = (_Float16*)(ws + (8ull  << 20));      //  32 MiB
    _Float16* QT   = (_Float16*)(ws + (40ull << 20));      //  32 MiB
    _Float16* KT   = (_Float16*)(ws + (72ull << 20));      //  32 MiB
    _Float16* Vb   = (_Float16*)(ws + (104ull << 20));     //  32 MiB
    _Float16* OcT  = (_Float16*)(ws + (136ull << 20));     //  32 MiB
    unsigned* omax = (unsigned*)(ws + (168ull << 20));     // 128 KiB

    convw_kernel<<<16384, 256, 0, stream>>>(Wq, Wk, Wv, Wo, Wcat);
    xpose_kernel<<<dim3(16, 32, 32), 256, 0, stream>>>(x, xT);
    initmax_kernel<<<128, 256, 0, stream>>>(omax);
    gemm1qk_kernel<<<dim3(4, 8, 32), 256, 0, stream>>>(Wcat, bq, xT, QT, QSCALE);
    gemm1qk_kernel<<<dim3(4, 8, 32), 256, 0, stream>>>(Wcat + (1ull << 20), bk, xT, KT, 1.0f);
    gemm1v_kernel<<<dim3(4, 8, 32), 256, 0, stream>>>(Wcat + (2ull << 20), bv, xT, Vb);
    attn_kernel<<<dim3(2, 16, 32), 256, 0, stream>>>(QT, KT, Vb, mask, OcT);
    gemm2_kernel<<<dim3(4, 8, 32), 256, 0, stream>>>(Wcat + (3ull << 20), OcT, omax);
    final_kernel<<<128, 256, 0, stream>>>(omax, bo, out);
}